// Round 6
// baseline (658.253 us; speedup 1.0000x reference)
//
#include <hip/hip_runtime.h>
#include <hip/hip_bf16.h>

#define B_ROWS 4096
#define M_ROWS 65536
#define DIM 512
#define TOPK 8
#define CAP 512
#define NR 24               // rescored candidates (top-NR by approx sim)
#define TAU 0.132583f       // 3/sqrt(512): ~88 candidates/query expected
#define FB_N 2048           // fallback merge entries = 256 threads * 8

typedef unsigned short u16;
typedef unsigned int u32;
typedef unsigned short u16x8 __attribute__((ext_vector_type(8)));
typedef __bf16 bf16x8 __attribute__((ext_vector_type(8)));
typedef float f32x4 __attribute__((ext_vector_type(4)));

__device__ inline u16 f2bf(float x) {
  unsigned u = __builtin_bit_cast(unsigned, x);
  u = (u + 0x7fffu + ((u >> 16) & 1u)) >> 16;  // RNE, finite inputs only
  return (u16)u;
}

// async global->LDS, 16B per lane; lds ptr must be wave-uniform (HW adds lane*16)
__device__ inline void gl_lds16(const u16* g, u16* l) {
  __builtin_amdgcn_global_load_lds(
      (const __attribute__((address_space(1))) u32*)g,
      (__attribute__((address_space(3))) u32*)l, 16, 0, 0);
}

// ---- normalize rows -> bf16 (one wave per row) ----
__global__ __launch_bounds__(256) void norm_kernel(const float* __restrict__ in,
                                                   u16* __restrict__ out, int nrows) {
  int gw = (int)((blockIdx.x * 256 + threadIdx.x) >> 6);
  int lane = threadIdx.x & 63;
  if (gw >= nrows) return;
  const float4* r = (const float4*)(in + (size_t)gw * DIM);
  float4 v0 = r[lane * 2 + 0];
  float4 v1 = r[lane * 2 + 1];
  float ss = v0.x*v0.x + v0.y*v0.y + v0.z*v0.z + v0.w*v0.w
           + v1.x*v1.x + v1.y*v1.y + v1.z*v1.z + v1.w*v1.w;
#pragma unroll
  for (int off = 32; off > 0; off >>= 1) ss += __shfl_xor(ss, off);
  float inv = 1.0f / fmaxf(sqrtf(ss), 1e-8f);
  u16x8 o;
  o[0]=f2bf(v0.x*inv); o[1]=f2bf(v0.y*inv); o[2]=f2bf(v0.z*inv); o[3]=f2bf(v0.w*inv);
  o[4]=f2bf(v1.x*inv); o[5]=f2bf(v1.y*inv); o[6]=f2bf(v1.z*inv); o[7]=f2bf(v1.w*inv);
  *(u16x8*)(out + (size_t)gw * DIM + lane * 8) = o;
}

// ---- PERSISTENT 256x256-tile GEMM: 256 blocks (1/CU), each block owns one
//      qtile and sweeps 16 consecutive mtiles; BK=32, 4-deep LDS ring,
//      counted vmcnt(8) carried ACROSS tile boundaries (one prologue/drain
//      per kernel), super-row XOR swizzle, setprio around MFMA.
//      Epilogue appends packed (bf16sim<<16 | idx) candidates. ----
__global__ __launch_bounds__(512, 1) void gemm_select(const u16* __restrict__ qn,
                                                      const u16* __restrict__ mn,
                                                      int* __restrict__ count,
                                                      u32* __restrict__ cand) {
  // ring of 4 K-step buffers: A[256 rows][32 elems] (16KB) + B same -> 128 KiB
  __shared__ u16 sA[4][8192];
  __shared__ u16 sB[4][8192];

  int bid0 = blockIdx.x;                      // 0..255, 1 per CU
  int xcd = bid0 & 7;                         // consecutive blocks round-robin XCDs
  int slot = bid0 >> 3;                       // 0..31 within XCD
  int mgroup = xcd * 2 + (slot & 1);          // 0..15 -> B-range pinned per XCD
  int qtile = slot >> 1;                      // 0..15
  int m0 = mgroup * 16;                       // starting mtile (16 consecutive)

  int tid = threadIdx.x;
  int lane = tid & 63;
  int w = tid >> 6;
  int wr = w >> 2, wc = w & 3;                // 2 x 4 wave grid; wave tile 128x64
  int rlo = lane & 15;
  int khi16 = (lane >> 4) << 4;               // byte offset of lane's 16B k-slice

  const u16* gA = qn + (size_t)qtile * 256 * DIM;

  // staging: dest byte d = i*8192 + tid*16 (linear; gl_lds dest is uniform+lane*16).
  // swizzle: within each 128B super-row, inner ^= (brow&7)<<4. Source is the
  // inverse permutation so that a swizzled READ returns logical data (rule #21).
  int brow_lo = tid >> 3;                     // 0..63 (+64 for issue 1)
  int innb = (tid & 7) << 4;                  // dest inner bytes 0..112
  int inns = innb ^ ((brow_lo & 7) << 4);     // logical inner for this dest slot
  int grow0 = brow_lo * 2 + (inns >> 6);      // logical row (issue 0)
  int gcole = (inns & 63) >> 1;               // element col within 32-elem row

  auto stA = [&](int buf, int kt) {
#pragma unroll
    for (int i2 = 0; i2 < 2; i2++)
      gl_lds16(gA + (size_t)(grow0 + i2 * 128) * DIM + kt * 32 + gcole,
               &sA[buf][i2 * 4096 + w * 512]);
  };
  auto stB = [&](int buf, const u16* gBb, int kt) {
#pragma unroll
    for (int i2 = 0; i2 < 2; i2++)
      gl_lds16(gBb + (size_t)(grow0 + i2 * 128) * DIM + kt * 32 + gcole,
               &sB[buf][i2 * 4096 + w * 512]);
  };
  auto rdA = [&](int buf, int mi) {
    int row = wr * 128 + mi * 16 + rlo;
    int brow = row >> 1;
    int phys = (brow << 7) + ((((row & 1) << 6) + khi16) ^ ((brow & 7) << 4));
    return __builtin_bit_cast(bf16x8, *(const u16x8*)((const char*)sA[buf] + phys));
  };
  auto rdB = [&](int buf, int ni) {
    int row = wc * 64 + ni * 16 + rlo;
    int brow = row >> 1;
    int phys = (brow << 7) + ((((row & 1) << 6) + khi16) ^ ((brow & 7) << 4));
    return __builtin_bit_cast(bf16x8, *(const u16x8*)((const char*)sB[buf] + phys));
  };

  f32x4 acc[8][4];
#pragma unroll
  for (int i = 0; i < 8; i++)
#pragma unroll
    for (int j = 0; j < 4; j++) {
      f32x4 z = {0.f, 0.f, 0.f, 0.f};
      acc[i][j] = z;
    }

  // one K-step: barrier (buf ready + prev readers done), 12 ds_read_b128,
  // issue next stage (stays in flight across future barriers), 32 MFMA.
  auto stepf = [&](int buf, int nbuf, int ktn, bool st, const u16* gBs) {
    __builtin_amdgcn_s_barrier();
    bf16x8 aF[8], bF[4];
#pragma unroll
    for (int mi = 0; mi < 8; mi++) aF[mi] = rdA(buf, mi);
#pragma unroll
    for (int ni = 0; ni < 4; ni++) bF[ni] = rdB(buf, ni);
    if (st) { stA(nbuf, ktn); stB(nbuf, gBs, ktn); }
    __builtin_amdgcn_s_setprio(1);
#pragma unroll
    for (int mi = 0; mi < 8; mi++)
#pragma unroll
      for (int ni = 0; ni < 4; ni++)
        acc[mi][ni] = __builtin_amdgcn_mfma_f32_16x16x32_bf16(aF[mi], bF[ni], acc[mi][ni], 0, 0, 0);
    __builtin_amdgcn_s_setprio(0);
  };

  int qbase = qtile * 256 + wr * 128 + (lane >> 4) * 4;

  // prologue (ONCE per kernel): stage K-steps 0,1,2 of first tile
  const u16* gB0 = mn + (size_t)m0 * 256 * DIM;
  stA(0, 0); stB(0, gB0, 0);
  stA(1, 1); stB(1, gB0, 1);
  stA(2, 2); stB(2, gB0, 2);

  for (int seg = 0; seg < 16; seg++) {
    const u16* gB = mn + (size_t)(m0 + seg) * 256 * DIM;
    const u16* gBn = mn + (size_t)(m0 + (seg < 15 ? seg + 1 : seg)) * 256 * DIM;
#pragma unroll
    for (int i = 0; i < 16; i++) {
      if (i < 14) {
        asm volatile("s_waitcnt vmcnt(8)" ::: "memory");
      } else if (i == 14) {
        if (seg < 15) asm volatile("s_waitcnt vmcnt(8)" ::: "memory");
        else          asm volatile("s_waitcnt vmcnt(4)" ::: "memory");
      } else {
        if (seg < 15) asm volatile("s_waitcnt vmcnt(8)" ::: "memory");
        else          asm volatile("s_waitcnt vmcnt(0)" ::: "memory");
      }
      bool st = (i <= 12) || (seg < 15);
      stepf(i & 3, (i + 3) & 3, (i + 3) & 15, st, (i <= 12) ? gB : gBn);
    }
    // per-tile C epilogue (registers + atomics only, no LDS/barrier):
    // C row (query) = (lane>>4)*4 + reg, col (mem) = lane&15  [m89 layout]
    int mbase = (m0 + seg) * 256 + wc * 64 + (lane & 15);
#pragma unroll
    for (int mi = 0; mi < 8; mi++)
#pragma unroll
      for (int ni = 0; ni < 4; ni++) {
#pragma unroll
        for (int r = 0; r < 4; r++) {
          float v = acc[mi][ni][r];
          if (v > TAU) {
            int qq = qbase + mi * 16 + r;
            u32 pk = (__builtin_bit_cast(u32, v) & 0xFFFF0000u) | (u32)(mbase + ni * 16);
            int pos = atomicAdd(&count[qq], 1);
            if (pos < CAP) cand[(size_t)qq * CAP + pos] = pk;
          }
        }
        f32x4 z = {0.f, 0.f, 0.f, 0.f};
        acc[mi][ni] = z;
      }
  }
}

// ---- per-query: top-NR by packed approx sim, fp64 rescore of those rows,
//      exact top-8, gather+mean ----
__global__ __launch_bounds__(256) void topk_kernel(const float* __restrict__ q,
                                                   const float* __restrict__ mem,
                                                   const int* __restrict__ count,
                                                   const u32* __restrict__ cand,
                                                   float* __restrict__ out) {
  __shared__ double s_sims[FB_N];   // fallback merge buffer
  __shared__ int s_cidx[FB_N];
  __shared__ double s_red[4];
  __shared__ int s_redj[4];
  __shared__ u32 s_pk[CAP];
  __shared__ int s_sel[NR];
  __shared__ double s_x[NR];
  __shared__ int s_win[TOPK];

  int b = blockIdx.x;
  int tid = threadIdx.x;
  int lane = tid & 63;
  int w = tid >> 6;

  const float* qrow = q + (size_t)b * DIM;
  const float4* qv = (const float4*)qrow;
  float4 q0 = qv[lane * 2], q1 = qv[lane * 2 + 1];
  double q8[8] = {q0.x, q0.y, q0.z, q0.w, q1.x, q1.y, q1.z, q1.w};
  double qq = 0;
#pragma unroll
  for (int e = 0; e < 8; e++) qq += q8[e] * q8[e];
#pragma unroll
  for (int off = 32; off > 0; off >>= 1) qq += __shfl_xor(qq, off);
  double qnorm = fmax(sqrt(qq), 1e-8);

  int c = count[b];
  if (c >= TOPK && c <= CAP) {
    // load packed candidates
    for (int j = tid; j < c; j += 256) s_pk[j] = cand[(size_t)b * CAP + j];
    __syncthreads();
    int nsel = c < NR ? c : NR;
    // wave 0 selects top-nsel by packed value (positive floats sort as ints)
    if (w == 0) {
      for (int r = 0; r < nsel; r++) {
        int best = -1, bj = -1;
        for (int j = lane; j < c; j += 64) {
          int v = (int)s_pk[j];
          if (v > best) { best = v; bj = j; }
        }
#pragma unroll
        for (int off = 32; off > 0; off >>= 1) {
          int ov = __shfl_down(best, off);
          int oj = __shfl_down(bj, off);
          if (ov > best) { best = ov; bj = oj; }
        }
        bj = __shfl(bj, 0);
        if (lane == 0) { s_sel[r] = (int)(s_pk[bj] & 0xFFFFu); s_pk[bj] = 0; }
      }
    }
    __syncthreads();
    // fp64 rescore of the nsel rows: wave w handles i = w, w+4, ...
    for (int i = w; i < nsel; i += 4) {
      int mi = s_sel[i];
      const float4* mv = (const float4*)(mem + (size_t)mi * DIM);
      float4 m0 = mv[lane * 2], m1 = mv[lane * 2 + 1];
      double m8[8] = {m0.x, m0.y, m0.z, m0.w, m1.x, m1.y, m1.z, m1.w};
      double dot = 0, mm = 0;
#pragma unroll
      for (int e = 0; e < 8; e++) { dot += q8[e] * m8[e]; mm += m8[e] * m8[e]; }
#pragma unroll
      for (int off = 32; off > 0; off >>= 1) {
        dot += __shfl_xor(dot, off);
        mm += __shfl_xor(mm, off);
      }
      if (lane == 0) s_x[i] = dot / (qnorm * fmax(sqrt(mm), 1e-8));
    }
    __syncthreads();
    // wave 0: exact top-8 of nsel (register argmax rounds)
    if (w == 0) {
      double myv = (lane < nsel) ? s_x[lane] : -1e300;
      int myrow = (lane < nsel) ? s_sel[lane] : -1;
      for (int r = 0; r < TOPK; r++) {
        double bv = myv; int bl = lane;
#pragma unroll
        for (int off = 32; off > 0; off >>= 1) {
          double ov = __shfl_down(bv, off);
          int ol = __shfl_down(bl, off);
          if (ov > bv) { bv = ov; bl = ol; }
        }
        bl = __shfl(bl, 0);
        int brow = __shfl(myrow, bl);
        if (lane == 0) s_win[r] = brow;
        if (lane == bl) myv = -1e300;
      }
    }
    __syncthreads();
  } else {
    // fallback (cold, correctness-only): full scan, per-thread top-8, block merge
    double tv[8]; int tix[8];
#pragma unroll
    for (int r = 0; r < 8; r++) { tv[r] = -1e300; tix[r] = -1; }
    for (int row = tid; row < M_ROWS; row += 256) {
      const float4* mv = (const float4*)(mem + (size_t)row * DIM);
      double dot = 0, mm = 0;
      for (int e = 0; e < DIM / 4; e++) {
        float4 m4 = mv[e], qk = qv[e];
        dot += (double)m4.x * qk.x + (double)m4.y * qk.y + (double)m4.z * qk.z + (double)m4.w * qk.w;
        mm  += (double)m4.x * m4.x + (double)m4.y * m4.y + (double)m4.z * m4.z + (double)m4.w * m4.w;
      }
      double sim = dot / (qnorm * fmax(sqrt(mm), 1e-8));
      int am = 0;
#pragma unroll
      for (int r = 1; r < 8; r++) if (tv[r] < tv[am]) am = r;
      if (sim > tv[am]) { tv[am] = sim; tix[am] = row; }
    }
#pragma unroll
    for (int r = 0; r < 8; r++) { s_sims[tid * 8 + r] = tv[r]; s_cidx[tid * 8 + r] = tix[r]; }
    __syncthreads();
    for (int r = 0; r < TOPK; r++) {
      double best = -1e300; int bj = -1;
      for (int j = tid; j < FB_N; j += 256) {
        double v = s_sims[j];
        if (v > best) { best = v; bj = j; }
      }
#pragma unroll
      for (int off = 32; off > 0; off >>= 1) {
        double ov = __shfl_down(best, off);
        int oj = __shfl_down(bj, off);
        if (ov > best) { best = ov; bj = oj; }
      }
      if (lane == 0) { s_red[w] = best; s_redj[w] = bj; }
      __syncthreads();
      if (tid == 0) {
        double bb = s_red[0]; int jj = s_redj[0];
        for (int i = 1; i < 4; i++) if (s_red[i] > bb) { bb = s_red[i]; jj = s_redj[i]; }
        s_win[r] = s_cidx[jj];
        s_sims[jj] = -1e300;
      }
      __syncthreads();
    }
  }

  // gather 8 winner rows, mean, write fp32 output
  float ax = 0.f, ay = 0.f;
#pragma unroll
  for (int r = 0; r < TOPK; r++) {
    const float2 v = *(const float2*)(mem + (size_t)s_win[r] * DIM + tid * 2);
    ax += v.x; ay += v.y;
  }
  float2 o; o.x = ax * 0.125f; o.y = ay * 0.125f;
  *(float2*)(out + (size_t)b * DIM + tid * 2) = o;
}

extern "C" void kernel_launch(void* const* d_in, const int* in_sizes, int n_in,
                              void* d_out, int out_size, void* d_ws, size_t ws_size,
                              hipStream_t stream) {
  (void)in_sizes; (void)n_in; (void)out_size; (void)ws_size;
  const float* q = (const float*)d_in[0];
  const float* mem = (const float*)d_in[1];
  float* out = (float*)d_out;

  char* ws = (char*)d_ws;
  u16* mn = (u16*)ws;                                        // 64 MB
  u16* qn = (u16*)(ws + (size_t)M_ROWS * DIM * 2);           // 4 MB
  int* count = (int*)(ws + (size_t)M_ROWS * DIM * 2 + (size_t)B_ROWS * DIM * 2);  // 16 KB
  u32* cand = (u32*)((char*)count + (size_t)B_ROWS * sizeof(int));                // 8 MB

  hipMemsetAsync(count, 0, B_ROWS * sizeof(int), stream);
  norm_kernel<<<M_ROWS / 4, 256, 0, stream>>>(mem, mn, M_ROWS);
  norm_kernel<<<B_ROWS / 4, 256, 0, stream>>>(q, qn, B_ROWS);
  gemm_select<<<256, 512, 0, stream>>>(qn, mn, count, cand);
  topk_kernel<<<B_ROWS, 256, 0, stream>>>(q, mem, count, cand, out);
}

// Round 7
// 499.737 us; speedup vs baseline: 1.3172x; 1.3172x over previous
//
#include <hip/hip_runtime.h>
#include <hip/hip_bf16.h>

#define B_ROWS 4096
#define M_ROWS 65536
#define DIM 512
#define TOPK 8
#define CAP 512
#define NR 24               // rescored candidates (top-NR by approx sim)
#define TAU 0.132583f       // 3/sqrt(512): ~88 candidates/query expected
#define FB_N 2048           // fallback merge entries = 256 threads * 8

typedef unsigned short u16;
typedef unsigned int u32;
typedef unsigned short u16x8 __attribute__((ext_vector_type(8)));
typedef __bf16 bf16x8 __attribute__((ext_vector_type(8)));
typedef float f32x4 __attribute__((ext_vector_type(4)));

__device__ inline u16 f2bf(float x) {
  unsigned u = __builtin_bit_cast(unsigned, x);
  u = (u + 0x7fffu + ((u >> 16) & 1u)) >> 16;  // RNE, finite inputs only
  return (u16)u;
}

// async global->LDS, 16B per lane; lds ptr must be wave-uniform (HW adds lane*16)
__device__ inline void gl_lds16(const u16* g, u16* l) {
  __builtin_amdgcn_global_load_lds(
      (const __attribute__((address_space(1))) u32*)g,
      (__attribute__((address_space(3))) u32*)l, 16, 0, 0);
}

// ---- normalize rows -> bf16 (one wave per row) ----
__global__ __launch_bounds__(256) void norm_kernel(const float* __restrict__ in,
                                                   u16* __restrict__ out, int nrows) {
  int gw = (int)((blockIdx.x * 256 + threadIdx.x) >> 6);
  int lane = threadIdx.x & 63;
  if (gw >= nrows) return;
  const float4* r = (const float4*)(in + (size_t)gw * DIM);
  float4 v0 = r[lane * 2 + 0];
  float4 v1 = r[lane * 2 + 1];
  float ss = v0.x*v0.x + v0.y*v0.y + v0.z*v0.z + v0.w*v0.w
           + v1.x*v1.x + v1.y*v1.y + v1.z*v1.z + v1.w*v1.w;
#pragma unroll
  for (int off = 32; off > 0; off >>= 1) ss += __shfl_xor(ss, off);
  float inv = 1.0f / fmaxf(sqrtf(ss), 1e-8f);
  u16x8 o;
  o[0]=f2bf(v0.x*inv); o[1]=f2bf(v0.y*inv); o[2]=f2bf(v0.z*inv); o[3]=f2bf(v0.w*inv);
  o[4]=f2bf(v1.x*inv); o[5]=f2bf(v1.y*inv); o[6]=f2bf(v1.z*inv); o[7]=f2bf(v1.w*inv);
  *(u16x8*)(out + (size_t)gw * DIM + lane * 8) = o;
}

// ---- m201-faithful 256x256 GEMM: BK=64, 2 dbuf x {A,B} x {k0,k1} quarters,
//      4 phases/K-tile, 1 quarter staged per phase (lead 6), vmcnt(8) at
//      ph2/ph4 only (peel 8->4->0), double-barrier phases with lgkmcnt(0),
//      super-row XOR swizzle, setprio around MFMA cluster. ----
__global__ __launch_bounds__(512, 2) void gemm_select(const u16* __restrict__ qn,
                                                      const u16* __restrict__ mn,
                                                      int* __restrict__ count,
                                                      u32* __restrict__ cand) {
  // quarter = [256 rows][32 elems] = 16 KB; [dbuf][khalf] x {A,B} = 128 KiB
  __shared__ u16 sA[2][2][8192];
  __shared__ u16 sB[2][2][8192];

  int bid0 = blockIdx.x;
  int bid = (bid0 & 7) * 512 + (bid0 >> 3);   // XCD swizzle (4096 % 8 == 0)
  int qtile = bid & 15;                       // 16 qtiles of 256
  int mtile = bid >> 4;                       // 256 mtiles of 256
  int tid = threadIdx.x;
  int lane = tid & 63;
  int w = tid >> 6;
  int wr = w >> 2, wc = w & 3;                // 2 x 4 wave grid; wave tile 128x64
  int rlo = lane & 15;
  int khi16 = (lane >> 4) << 4;               // byte offset of lane's 16B k-slice

  const u16* gA = qn + (size_t)qtile * 256 * DIM;
  const u16* gB = mn + (size_t)mtile * 256 * DIM;

  // staging geometry (R4-verified): dest byte = i2*8192 + tid*16 (linear);
  // source pre-swizzled so a swizzled READ returns logical data (rule #21).
  int brow_lo = tid >> 3;                     // super-row 0..63 per 8KB issue
  int innb = (tid & 7) << 4;                  // dest inner bytes 0..112
  int inns = innb ^ ((brow_lo & 7) << 4);     // logical inner for this dest slot
  int grow0 = brow_lo * 2 + (inns >> 6);      // logical row (issue 0)
  int gcole = (inns & 63) >> 1;               // element col within 32-elem row

  // quarter stream: q = 4*tile + sub; sub 0:A-k0 1:B-k0 2:A-k1 3:B-k1
  auto stage = [&](int q) {
    int tile = q >> 2;
    int dbuf = tile & 1;
    int sub = q & 3;
    int kh = sub >> 1;
    int k0 = tile * 64 + kh * 32;
    const u16* g = (sub & 1) ? gB : gA;
    u16* l = (sub & 1) ? &sB[dbuf][kh][0] : &sA[dbuf][kh][0];
#pragma unroll
    for (int i2 = 0; i2 < 2; i2++)
      gl_lds16(g + (size_t)(grow0 + i2 * 128) * DIM + k0 + gcole,
               l + i2 * 4096 + w * 512);
  };
  auto rdA = [&](int dbuf, int kh, int mi) {
    int row = wr * 128 + mi * 16 + rlo;
    int brow = row >> 1;
    int phys = (brow << 7) + ((((row & 1) << 6) + khi16) ^ ((brow & 7) << 4));
    return __builtin_bit_cast(bf16x8, *(const u16x8*)((const char*)&sA[dbuf][kh][0] + phys));
  };
  auto rdB = [&](int dbuf, int kh, int ni) {
    int row = wc * 64 + ni * 16 + rlo;
    int brow = row >> 1;
    int phys = (brow << 7) + ((((row & 1) << 6) + khi16) ^ ((brow & 7) << 4));
    return __builtin_bit_cast(bf16x8, *(const u16x8*)((const char*)&sB[dbuf][kh][0] + phys));
  };

  f32x4 acc[8][4];
#pragma unroll
  for (int i = 0; i < 8; i++)
#pragma unroll
    for (int j = 0; j < 4; j++) {
      f32x4 z = {0.f, 0.f, 0.f, 0.f};
      acc[i][j] = z;
    }
  bf16x8 aF[8], b0, b1;

  // prologue: stage quarters 0..5 (tile0 full + tile1 A-k0,B-k0); need q0,q1
  stage(0); stage(1); stage(2); stage(3); stage(4); stage(5);
  asm volatile("s_waitcnt vmcnt(8)" ::: "memory");
  __builtin_amdgcn_s_barrier();

#define PH_TAIL(NIP0, NIP1)                                                     \
  __builtin_amdgcn_s_barrier();                                                 \
  asm volatile("s_waitcnt lgkmcnt(0)" ::: "memory");                            \
  __builtin_amdgcn_sched_barrier(0);                                            \
  __builtin_amdgcn_s_setprio(1);                                                \
  _Pragma("unroll")                                                             \
  for (int mi = 0; mi < 8; mi++) {                                              \
    acc[mi][NIP0] = __builtin_amdgcn_mfma_f32_16x16x32_bf16(aF[mi], b0, acc[mi][NIP0], 0, 0, 0); \
    acc[mi][NIP1] = __builtin_amdgcn_mfma_f32_16x16x32_bf16(aF[mi], b1, acc[mi][NIP1], 0, 0, 0); \
  }                                                                             \
  __builtin_amdgcn_s_setprio(0);                                                \
  __builtin_amdgcn_s_barrier();

#pragma unroll
  for (int t = 0; t < 8; t++) {
    int db = t & 1;
    // ---- ph1: aF<-A-k0 (8 rd), b<-B-k0 ni0,1; stage q4t+6 (t+1 A-k1) ----
#pragma unroll
    for (int mi = 0; mi < 8; mi++) aF[mi] = rdA(db, 0, mi);
    b0 = rdB(db, 0, 0); b1 = rdB(db, 0, 1);
    if (4 * t + 6 < 32) stage(4 * t + 6);
    PH_TAIL(0, 1)
    // ---- ph2: b<-B-k0 ni2,3; stage q4t+7 (t+1 B-k1); vmcnt for t's k1 ----
    b0 = rdB(db, 0, 2); b1 = rdB(db, 0, 3);
    if (4 * t + 7 < 32) stage(4 * t + 7);
    if (t < 7) asm volatile("s_waitcnt vmcnt(8)" ::: "memory");
    else       asm volatile("s_waitcnt vmcnt(0)" ::: "memory");
    PH_TAIL(2, 3)
    // ---- ph3: aF<-A-k1 (8 rd), b<-B-k1 ni0,1; stage q4t+8 (t+2 A-k0) ----
#pragma unroll
    for (int mi = 0; mi < 8; mi++) aF[mi] = rdA(db, 1, mi);
    b0 = rdB(db, 1, 0); b1 = rdB(db, 1, 1);
    if (4 * t + 8 < 32) stage(4 * t + 8);
    PH_TAIL(0, 1)
    // ---- ph4: b<-B-k1 ni2,3; stage q4t+9 (t+2 B-k0); vmcnt for t+1's k0 ----
    b0 = rdB(db, 1, 2); b1 = rdB(db, 1, 3);
    if (4 * t + 9 < 32) stage(4 * t + 9);
    if (t < 6)      asm volatile("s_waitcnt vmcnt(8)" ::: "memory");
    else if (t == 6) asm volatile("s_waitcnt vmcnt(4)" ::: "memory");
    PH_TAIL(2, 3)
  }
#undef PH_TAIL

  // epilogue: C row (query) = (lane>>4)*4 + reg, col (mem) = lane&15  [m89 layout]
  int qbase = qtile * 256 + wr * 128 + (lane >> 4) * 4;
  int mbase = mtile * 256 + wc * 64 + (lane & 15);
#pragma unroll
  for (int mi = 0; mi < 8; mi++)
#pragma unroll
    for (int ni = 0; ni < 4; ni++)
#pragma unroll
      for (int r = 0; r < 4; r++) {
        float v = acc[mi][ni][r];
        if (v > TAU) {
          int qq = qbase + mi * 16 + r;
          u32 pk = (__builtin_bit_cast(u32, v) & 0xFFFF0000u) | (u32)(mbase + ni * 16);
          int pos = atomicAdd(&count[qq], 1);
          if (pos < CAP) cand[(size_t)qq * CAP + pos] = pk;
        }
      }
}

// ---- per-query: top-NR by packed approx sim, fp64 rescore of those rows,
//      exact top-8, gather+mean ----
__global__ __launch_bounds__(256) void topk_kernel(const float* __restrict__ q,
                                                   const float* __restrict__ mem,
                                                   const int* __restrict__ count,
                                                   const u32* __restrict__ cand,
                                                   float* __restrict__ out) {
  __shared__ double s_sims[FB_N];   // fallback merge buffer
  __shared__ int s_cidx[FB_N];
  __shared__ double s_red[4];
  __shared__ int s_redj[4];
  __shared__ u32 s_pk[CAP];
  __shared__ int s_sel[NR];
  __shared__ double s_x[NR];
  __shared__ int s_win[TOPK];

  int b = blockIdx.x;
  int tid = threadIdx.x;
  int lane = tid & 63;
  int w = tid >> 6;

  const float* qrow = q + (size_t)b * DIM;
  const float4* qv = (const float4*)qrow;
  float4 q0 = qv[lane * 2], q1 = qv[lane * 2 + 1];
  double q8[8] = {q0.x, q0.y, q0.z, q0.w, q1.x, q1.y, q1.z, q1.w};
  double qq = 0;
#pragma unroll
  for (int e = 0; e < 8; e++) qq += q8[e] * q8[e];
#pragma unroll
  for (int off = 32; off > 0; off >>= 1) qq += __shfl_xor(qq, off);
  double qnorm = fmax(sqrt(qq), 1e-8);

  int c = count[b];
  if (c >= TOPK && c <= CAP) {
    for (int j = tid; j < c; j += 256) s_pk[j] = cand[(size_t)b * CAP + j];
    __syncthreads();
    int nsel = c < NR ? c : NR;
    if (w == 0) {
      for (int r = 0; r < nsel; r++) {
        int best = -1, bj = -1;
        for (int j = lane; j < c; j += 64) {
          int v = (int)s_pk[j];
          if (v > best) { best = v; bj = j; }
        }
#pragma unroll
        for (int off = 32; off > 0; off >>= 1) {
          int ov = __shfl_down(best, off);
          int oj = __shfl_down(bj, off);
          if (ov > best) { best = ov; bj = oj; }
        }
        bj = __shfl(bj, 0);
        if (lane == 0) { s_sel[r] = (int)(s_pk[bj] & 0xFFFFu); s_pk[bj] = 0; }
      }
    }
    __syncthreads();
    for (int i = w; i < nsel; i += 4) {
      int mi = s_sel[i];
      const float4* mv = (const float4*)(mem + (size_t)mi * DIM);
      float4 m0 = mv[lane * 2], m1 = mv[lane * 2 + 1];
      double m8[8] = {m0.x, m0.y, m0.z, m0.w, m1.x, m1.y, m1.z, m1.w};
      double dot = 0, mm = 0;
#pragma unroll
      for (int e = 0; e < 8; e++) { dot += q8[e] * m8[e]; mm += m8[e] * m8[e]; }
#pragma unroll
      for (int off = 32; off > 0; off >>= 1) {
        dot += __shfl_xor(dot, off);
        mm += __shfl_xor(mm, off);
      }
      if (lane == 0) s_x[i] = dot / (qnorm * fmax(sqrt(mm), 1e-8));
    }
    __syncthreads();
    if (w == 0) {
      double myv = (lane < nsel) ? s_x[lane] : -1e300;
      int myrow = (lane < nsel) ? s_sel[lane] : -1;
      for (int r = 0; r < TOPK; r++) {
        double bv = myv; int bl = lane;
#pragma unroll
        for (int off = 32; off > 0; off >>= 1) {
          double ov = __shfl_down(bv, off);
          int ol = __shfl_down(bl, off);
          if (ov > bv) { bv = ov; bl = ol; }
        }
        bl = __shfl(bl, 0);
        int brow = __shfl(myrow, bl);
        if (lane == 0) s_win[r] = brow;
        if (lane == bl) myv = -1e300;
      }
    }
    __syncthreads();
  } else {
    // fallback (cold, correctness-only): full scan, per-thread top-8, block merge
    double tv[8]; int tix[8];
#pragma unroll
    for (int r = 0; r < 8; r++) { tv[r] = -1e300; tix[r] = -1; }
    for (int row = tid; row < M_ROWS; row += 256) {
      const float4* mv = (const float4*)(mem + (size_t)row * DIM);
      double dot = 0, mm = 0;
      for (int e = 0; e < DIM / 4; e++) {
        float4 m4 = mv[e], qk = qv[e];
        dot += (double)m4.x * qk.x + (double)m4.y * qk.y + (double)m4.z * qk.z + (double)m4.w * qk.w;
        mm  += (double)m4.x * m4.x + (double)m4.y * m4.y + (double)m4.z * m4.z + (double)m4.w * m4.w;
      }
      double sim = dot / (qnorm * fmax(sqrt(mm), 1e-8));
      int am = 0;
#pragma unroll
      for (int r = 1; r < 8; r++) if (tv[r] < tv[am]) am = r;
      if (sim > tv[am]) { tv[am] = sim; tix[am] = row; }
    }
#pragma unroll
    for (int r = 0; r < 8; r++) { s_sims[tid * 8 + r] = tv[r]; s_cidx[tid * 8 + r] = tix[r]; }
    __syncthreads();
    for (int r = 0; r < TOPK; r++) {
      double best = -1e300; int bj = -1;
      for (int j = tid; j < FB_N; j += 256) {
        double v = s_sims[j];
        if (v > best) { best = v; bj = j; }
      }
#pragma unroll
      for (int off = 32; off > 0; off >>= 1) {
        double ov = __shfl_down(best, off);
        int oj = __shfl_down(bj, off);
        if (ov > best) { best = ov; bj = oj; }
      }
      if (lane == 0) { s_red[w] = best; s_redj[w] = bj; }
      __syncthreads();
      if (tid == 0) {
        double bb = s_red[0]; int jj = s_redj[0];
        for (int i = 1; i < 4; i++) if (s_red[i] > bb) { bb = s_red[i]; jj = s_redj[i]; }
        s_win[r] = s_cidx[jj];
        s_sims[jj] = -1e300;
      }
      __syncthreads();
    }
  }

  // gather 8 winner rows, mean, write fp32 output
  float ax = 0.f, ay = 0.f;
#pragma unroll
  for (int r = 0; r < TOPK; r++) {
    const float2 v = *(const float2*)(mem + (size_t)s_win[r] * DIM + tid * 2);
    ax += v.x; ay += v.y;
  }
  float2 o; o.x = ax * 0.125f; o.y = ay * 0.125f;
  *(float2*)(out + (size_t)b * DIM + tid * 2) = o;
}

extern "C" void kernel_launch(void* const* d_in, const int* in_sizes, int n_in,
                              void* d_out, int out_size, void* d_ws, size_t ws_size,
                              hipStream_t stream) {
  (void)in_sizes; (void)n_in; (void)out_size; (void)ws_size;
  const float* q = (const float*)d_in[0];
  const float* mem = (const float*)d_in[1];
  float* out = (float*)d_out;

  char* ws = (char*)d_ws;
  u16* mn = (u16*)ws;                                        // 64 MB
  u16* qn = (u16*)(ws + (size_t)M_ROWS * DIM * 2);           // 4 MB
  int* count = (int*)(ws + (size_t)M_ROWS * DIM * 2 + (size_t)B_ROWS * DIM * 2);  // 16 KB
  u32* cand = (u32*)((char*)count + (size_t)B_ROWS * sizeof(int));                // 8 MB

  hipMemsetAsync(count, 0, B_ROWS * sizeof(int), stream);
  norm_kernel<<<M_ROWS / 4, 256, 0, stream>>>(mem, mn, M_ROWS);
  norm_kernel<<<B_ROWS / 4, 256, 0, stream>>>(q, qn, B_ROWS);
  gemm_select<<<(B_ROWS / 256) * (M_ROWS / 256), 512, 0, stream>>>(qn, mn, count, cand);
  topk_kernel<<<B_ROWS, 256, 0, stream>>>(q, mem, count, cand, out);
}

// Round 8
// 445.755 us; speedup vs baseline: 1.4767x; 1.1211x over previous
//
#include <hip/hip_runtime.h>
#include <hip/hip_bf16.h>

#define B_ROWS 4096
#define M_ROWS 65536
#define DIM 512
#define TOPK 8
#define CAP 512
#define NR 24               // rescored candidates (top-NR by approx sim)
#define TAU 0.132583f       // 3/sqrt(512): ~88 candidates/query expected
#define FB_N 2048           // fallback merge entries = 256 threads * 8

typedef unsigned short u16;
typedef unsigned int u32;
typedef unsigned short u16x8 __attribute__((ext_vector_type(8)));
typedef __bf16 bf16x8 __attribute__((ext_vector_type(8)));
typedef float f32x4 __attribute__((ext_vector_type(4)));

__device__ inline u16 f2bf(float x) {
  unsigned u = __builtin_bit_cast(unsigned, x);
  u = (u + 0x7fffu + ((u >> 16) & 1u)) >> 16;  // RNE, finite inputs only
  return (u16)u;
}

// async global->LDS, 16B per lane; lds ptr must be wave-uniform (HW adds lane*16)
__device__ inline void gl_lds16(const u16* g, u16* l) {
  __builtin_amdgcn_global_load_lds(
      (const __attribute__((address_space(1))) u32*)g,
      (__attribute__((address_space(3))) u32*)l, 16, 0, 0);
}

// ---- normalize rows -> bf16 (one wave per row) ----
__global__ __launch_bounds__(256) void norm_kernel(const float* __restrict__ in,
                                                   u16* __restrict__ out, int nrows) {
  int gw = (int)((blockIdx.x * 256 + threadIdx.x) >> 6);
  int lane = threadIdx.x & 63;
  if (gw >= nrows) return;
  const float4* r = (const float4*)(in + (size_t)gw * DIM);
  float4 v0 = r[lane * 2 + 0];
  float4 v1 = r[lane * 2 + 1];
  float ss = v0.x*v0.x + v0.y*v0.y + v0.z*v0.z + v0.w*v0.w
           + v1.x*v1.x + v1.y*v1.y + v1.z*v1.z + v1.w*v1.w;
#pragma unroll
  for (int off = 32; off > 0; off >>= 1) ss += __shfl_xor(ss, off);
  float inv = 1.0f / fmaxf(sqrtf(ss), 1e-8f);
  u16x8 o;
  o[0]=f2bf(v0.x*inv); o[1]=f2bf(v0.y*inv); o[2]=f2bf(v0.z*inv); o[3]=f2bf(v0.w*inv);
  o[4]=f2bf(v1.x*inv); o[5]=f2bf(v1.y*inv); o[6]=f2bf(v1.z*inv); o[7]=f2bf(v1.w*inv);
  *(u16x8*)(out + (size_t)gw * DIM + lane * 8) = o;
}

// ---- 128x128 tile, BK=32, 4 waves, ring-3 LDS (48KB -> 3 blocks/CU),
//      counted vmcnt(4) ring (peel 4->0), super-row XOR swizzle,
//      setprio around MFMA. Cross-block co-residency hides barrier drains. ----
__global__ __launch_bounds__(256, 3) void gemm_select(const u16* __restrict__ qn,
                                                      const u16* __restrict__ mn,
                                                      int* __restrict__ count,
                                                      u32* __restrict__ cand) {
  // ring of 3 K-step buffers: A[128 rows][32 elems] (8KB) + B same -> 48 KiB
  __shared__ u16 sA[3][4096];
  __shared__ u16 sB[3][4096];

  // bijective XCD mapping: XCD k owns (qband = k>>1, mhalf = k&1):
  // 8 qtiles (1MB qn, L2-resident) x 256 mtiles; consecutive blocks on an
  // XCD share an mtile (qtile-inner) -> mn fetched ~once per chip.
  int bid0 = blockIdx.x;
  int b1 = (bid0 & 7) * 2048 + (bid0 >> 3);
  int qtile = (b1 >> 12) * 8 + (b1 & 7);      // 0..31
  int mtile = (b1 >> 3) & 511;                // 0..511

  int tid = threadIdx.x;
  int lane = tid & 63;
  int w = tid >> 6;
  int wr = w >> 1, wc = w & 1;                // 2 x 2 wave grid; wave tile 64x64
  int rlo = lane & 15;
  int khi16 = (lane >> 4) << 4;               // byte offset of lane's 16B k-slice

  const u16* gA = qn + (size_t)qtile * 128 * DIM;
  const u16* gB = mn + (size_t)mtile * 128 * DIM;

  // staging: per issue 4KB (256 thr x 16B), dest byte = tid*16 (linear).
  // super-row (128B) XOR swizzle; source pre-swizzled (inverse permutation)
  // so a swizzled READ returns logical data (rule #21). Verified R4: 0 conflicts.
  int brow_lo = tid >> 3;                     // super-row 0..31 per 4KB issue
  int innb = (tid & 7) << 4;                  // dest inner bytes 0..112
  int inns = innb ^ ((brow_lo & 7) << 4);     // logical inner for this dest slot
  int grow0 = brow_lo * 2 + (inns >> 6);      // logical row (issue 0)
  int gcole = (inns & 63) >> 1;               // element col within 32-elem row

  auto stage = [&](int slot, int kt) {        // 4 vmem ops per wave
#pragma unroll
    for (int i2 = 0; i2 < 2; i2++) {
      gl_lds16(gA + (size_t)(grow0 + i2 * 64) * DIM + kt * 32 + gcole,
               &sA[slot][i2 * 2048 + w * 512]);
      gl_lds16(gB + (size_t)(grow0 + i2 * 64) * DIM + kt * 32 + gcole,
               &sB[slot][i2 * 2048 + w * 512]);
    }
  };
  auto rdA = [&](int slot, int mi) {
    int row = wr * 64 + mi * 16 + rlo;
    int brow = row >> 1;
    int phys = (brow << 7) + ((((row & 1) << 6) + khi16) ^ ((brow & 7) << 4));
    return __builtin_bit_cast(bf16x8, *(const u16x8*)((const char*)sA[slot] + phys));
  };
  auto rdB = [&](int slot, int ni) {
    int row = wc * 64 + ni * 16 + rlo;
    int brow = row >> 1;
    int phys = (brow << 7) + ((((row & 1) << 6) + khi16) ^ ((brow & 7) << 4));
    return __builtin_bit_cast(bf16x8, *(const u16x8*)((const char*)sB[slot] + phys));
  };

  f32x4 acc[4][4];
#pragma unroll
  for (int i = 0; i < 4; i++)
#pragma unroll
    for (int j = 0; j < 4; j++) {
      f32x4 z = {0.f, 0.f, 0.f, 0.f};
      acc[i][j] = z;
    }

  // prologue: stage K-steps 0,1 into slots 0,1 (8 vmem/wave in flight)
  stage(0, 0);
  stage(1, 1);

  int cs = 0;  // slot of current K-step
  for (int t = 0; t < 16; t++) {
    // counted wait: buf t's 4 oldest land; buf t+1's 4 stay in flight
    if (t < 15) asm volatile("s_waitcnt vmcnt(4)" ::: "memory");
    else        asm volatile("s_waitcnt vmcnt(0)" ::: "memory");
    __builtin_amdgcn_s_barrier();
    bf16x8 aF[4], bF[4];
#pragma unroll
    for (int mi = 0; mi < 4; mi++) aF[mi] = rdA(cs, mi);
#pragma unroll
    for (int ni = 0; ni < 4; ni++) bF[ni] = rdB(cs, ni);
    if (t <= 13) {
      int ns = cs + 2; if (ns >= 3) ns -= 3;
      stage(ns, t + 2);  // overwrites buf t-1's slot: its readers done pre-barrier
    }
    __builtin_amdgcn_s_setprio(1);
#pragma unroll
    for (int mi = 0; mi < 4; mi++)
#pragma unroll
      for (int ni = 0; ni < 4; ni++)
        acc[mi][ni] = __builtin_amdgcn_mfma_f32_16x16x32_bf16(aF[mi], bF[ni], acc[mi][ni], 0, 0, 0);
    __builtin_amdgcn_s_setprio(0);
    cs = (cs + 1 == 3) ? 0 : cs + 1;
  }

  // epilogue: C row (query) = (lane>>4)*4 + reg, col (mem) = lane&15  [m89 layout]
  int qbase = qtile * 128 + wr * 64 + (lane >> 4) * 4;
  int mbase = mtile * 128 + wc * 64 + (lane & 15);
#pragma unroll
  for (int mi = 0; mi < 4; mi++)
#pragma unroll
    for (int ni = 0; ni < 4; ni++)
#pragma unroll
      for (int r = 0; r < 4; r++) {
        float v = acc[mi][ni][r];
        if (v > TAU) {
          int qq = qbase + mi * 16 + r;
          u32 pk = (__builtin_bit_cast(u32, v) & 0xFFFF0000u) | (u32)(mbase + ni * 16);
          int pos = atomicAdd(&count[qq], 1);
          if (pos < CAP) cand[(size_t)qq * CAP + pos] = pk;
        }
      }
}

// ---- per-query: top-NR by packed approx sim, fp64 rescore of those rows,
//      exact top-8, gather+mean ----
__global__ __launch_bounds__(256) void topk_kernel(const float* __restrict__ q,
                                                   const float* __restrict__ mem,
                                                   const int* __restrict__ count,
                                                   const u32* __restrict__ cand,
                                                   float* __restrict__ out) {
  __shared__ double s_sims[FB_N];   // fallback merge buffer
  __shared__ int s_cidx[FB_N];
  __shared__ double s_red[4];
  __shared__ int s_redj[4];
  __shared__ u32 s_pk[CAP];
  __shared__ int s_sel[NR];
  __shared__ double s_x[NR];
  __shared__ int s_win[TOPK];

  int b = blockIdx.x;
  int tid = threadIdx.x;
  int lane = tid & 63;
  int w = tid >> 6;

  const float* qrow = q + (size_t)b * DIM;
  const float4* qv = (const float4*)qrow;
  float4 q0 = qv[lane * 2], q1 = qv[lane * 2 + 1];
  double q8[8] = {q0.x, q0.y, q0.z, q0.w, q1.x, q1.y, q1.z, q1.w};
  double qq = 0;
#pragma unroll
  for (int e = 0; e < 8; e++) qq += q8[e] * q8[e];
#pragma unroll
  for (int off = 32; off > 0; off >>= 1) qq += __shfl_xor(qq, off);
  double qnorm = fmax(sqrt(qq), 1e-8);

  int c = count[b];
  if (c >= TOPK && c <= CAP) {
    for (int j = tid; j < c; j += 256) s_pk[j] = cand[(size_t)b * CAP + j];
    __syncthreads();
    int nsel = c < NR ? c : NR;
    if (w == 0) {
      for (int r = 0; r < nsel; r++) {
        int best = -1, bj = -1;
        for (int j = lane; j < c; j += 64) {
          int v = (int)s_pk[j];
          if (v > best) { best = v; bj = j; }
        }
#pragma unroll
        for (int off = 32; off > 0; off >>= 1) {
          int ov = __shfl_down(best, off);
          int oj = __shfl_down(bj, off);
          if (ov > best) { best = ov; bj = oj; }
        }
        bj = __shfl(bj, 0);
        if (lane == 0) { s_sel[r] = (int)(s_pk[bj] & 0xFFFFu); s_pk[bj] = 0; }
      }
    }
    __syncthreads();
    for (int i = w; i < nsel; i += 4) {
      int mi = s_sel[i];
      const float4* mv = (const float4*)(mem + (size_t)mi * DIM);
      float4 m0 = mv[lane * 2], m1 = mv[lane * 2 + 1];
      double m8[8] = {m0.x, m0.y, m0.z, m0.w, m1.x, m1.y, m1.z, m1.w};
      double dot = 0, mm = 0;
#pragma unroll
      for (int e = 0; e < 8; e++) { dot += q8[e] * m8[e]; mm += m8[e] * m8[e]; }
#pragma unroll
      for (int off = 32; off > 0; off >>= 1) {
        dot += __shfl_xor(dot, off);
        mm += __shfl_xor(mm, off);
      }
      if (lane == 0) s_x[i] = dot / (qnorm * fmax(sqrt(mm), 1e-8));
    }
    __syncthreads();
    if (w == 0) {
      double myv = (lane < nsel) ? s_x[lane] : -1e300;
      int myrow = (lane < nsel) ? s_sel[lane] : -1;
      for (int r = 0; r < TOPK; r++) {
        double bv = myv; int bl = lane;
#pragma unroll
        for (int off = 32; off > 0; off >>= 1) {
          double ov = __shfl_down(bv, off);
          int ol = __shfl_down(bl, off);
          if (ov > bv) { bv = ov; bl = ol; }
        }
        bl = __shfl(bl, 0);
        int brow = __shfl(myrow, bl);
        if (lane == 0) s_win[r] = brow;
        if (lane == bl) myv = -1e300;
      }
    }
    __syncthreads();
  } else {
    // fallback (cold, correctness-only): full scan, per-thread top-8, block merge
    double tv[8]; int tix[8];
#pragma unroll
    for (int r = 0; r < 8; r++) { tv[r] = -1e300; tix[r] = -1; }
    for (int row = tid; row < M_ROWS; row += 256) {
      const float4* mv = (const float4*)(mem + (size_t)row * DIM);
      double dot = 0, mm = 0;
      for (int e = 0; e < DIM / 4; e++) {
        float4 m4 = mv[e], qk = qv[e];
        dot += (double)m4.x * qk.x + (double)m4.y * qk.y + (double)m4.z * qk.z + (double)m4.w * qk.w;
        mm  += (double)m4.x * m4.x + (double)m4.y * m4.y + (double)m4.z * m4.z + (double)m4.w * m4.w;
      }
      double sim = dot / (qnorm * fmax(sqrt(mm), 1e-8));
      int am = 0;
#pragma unroll
      for (int r = 1; r < 8; r++) if (tv[r] < tv[am]) am = r;
      if (sim > tv[am]) { tv[am] = sim; tix[am] = row; }
    }
#pragma unroll
    for (int r = 0; r < 8; r++) { s_sims[tid * 8 + r] = tv[r]; s_cidx[tid * 8 + r] = tix[r]; }
    __syncthreads();
    for (int r = 0; r < TOPK; r++) {
      double best = -1e300; int bj = -1;
      for (int j = tid; j < FB_N; j += 256) {
        double v = s_sims[j];
        if (v > best) { best = v; bj = j; }
      }
#pragma unroll
      for (int off = 32; off > 0; off >>= 1) {
        double ov = __shfl_down(best, off);
        int oj = __shfl_down(bj, off);
        if (ov > best) { best = ov; bj = oj; }
      }
      if (lane == 0) { s_red[w] = best; s_redj[w] = bj; }
      __syncthreads();
      if (tid == 0) {
        double bb = s_red[0]; int jj = s_redj[0];
        for (int i = 1; i < 4; i++) if (s_red[i] > bb) { bb = s_red[i]; jj = s_redj[i]; }
        s_win[r] = s_cidx[jj];
        s_sims[jj] = -1e300;
      }
      __syncthreads();
    }
  }

  // gather 8 winner rows, mean, write fp32 output
  float ax = 0.f, ay = 0.f;
#pragma unroll
  for (int r = 0; r < TOPK; r++) {
    const float2 v = *(const float2*)(mem + (size_t)s_win[r] * DIM + tid * 2);
    ax += v.x; ay += v.y;
  }
  float2 o; o.x = ax * 0.125f; o.y = ay * 0.125f;
  *(float2*)(out + (size_t)b * DIM + tid * 2) = o;
}

extern "C" void kernel_launch(void* const* d_in, const int* in_sizes, int n_in,
                              void* d_out, int out_size, void* d_ws, size_t ws_size,
                              hipStream_t stream) {
  (void)in_sizes; (void)n_in; (void)out_size; (void)ws_size;
  const float* q = (const float*)d_in[0];
  const float* mem = (const float*)d_in[1];
  float* out = (float*)d_out;

  char* ws = (char*)d_ws;
  u16* mn = (u16*)ws;                                        // 64 MB
  u16* qn = (u16*)(ws + (size_t)M_ROWS * DIM * 2);           // 4 MB
  int* count = (int*)(ws + (size_t)M_ROWS * DIM * 2 + (size_t)B_ROWS * DIM * 2);  // 16 KB
  u32* cand = (u32*)((char*)count + (size_t)B_ROWS * sizeof(int));                // 8 MB

  hipMemsetAsync(count, 0, B_ROWS * sizeof(int), stream);
  norm_kernel<<<M_ROWS / 4, 256, 0, stream>>>(mem, mn, M_ROWS);
  norm_kernel<<<B_ROWS / 4, 256, 0, stream>>>(q, qn, B_ROWS);
  gemm_select<<<(B_ROWS / 128) * (M_ROWS / 128), 256, 0, stream>>>(qn, mn, count, cand);
  topk_kernel<<<B_ROWS, 256, 0, stream>>>(q, mem, count, cand, out);
}